// Round 12
// baseline (925.594 us; speedup 1.0000x reference)
//
#include <hip/hip_runtime.h>

// Multiscale Residual VQ (VAR-style), MI355X gfx950.
// Round 17:
//   - k_dist1 epilogue on 32-bit keys: payload (tn*16+l15 = n - n0 - wn*64)
//     embedded in the low 6 mantissa bits of the monotone f32 key
//     (perturbation <= ~0.008 on O(1000) dists, << hh-approx error 0.3 and
//     DELTA 0.5; deterministic; within-block ties -> lowest n). Top-2 DPP
//     tree now u32: 6 insts/step vs ~16 (round-16's u64 cmp/sel chains were
//     the measured VALUBusy-47% blob). bm2 format unchanged (key<<32 | n).
//   - k_phi_s for s<=4 (M<=64): 1 block/m, q row (exact f32) in LDS, 6 dots
//     per thread over (wh + wl/4096) f32 weights (~1e-7, same error class as
//     the MFMA dual-split). Replaces a 12-block latency-bound k_phi launch.
// Everything else unchanged from round 16 (700us passing).

#define ND 512
#define NCB 4096
#define DELTA 0.5f

typedef _Float16 half8v __attribute__((ext_vector_type(8)));
typedef _Float16 half4v __attribute__((ext_vector_type(4)));
typedef float floatx4 __attribute__((ext_vector_type(4)));

struct HL { _Float16 h, l; };

__device__ __forceinline__ HL split2(float v) {
    HL r;
    r.h = (_Float16)v;
    r.l = (_Float16)((v - (float)r.h) * 4096.0f);
    return r;
}

__device__ __forceinline__ unsigned long long pack_dist(float d, int n) {
    unsigned u = __float_as_uint(d);
    u = (u & 0x80000000u) ? ~u : (u | 0x80000000u);   // monotone total order
    return ((unsigned long long)u << 32) | (unsigned)n; // tie -> lowest idx
}

__device__ __forceinline__ float unpack_dist(unsigned long long p) {
    unsigned u = (unsigned)(p >> 32);
    u = (u & 0x80000000u) ? (u & 0x7fffffffu) : ~u;
    return __uint_as_float(u);
}

// u32 DPP row_ror move (ctrl literal); bound_ctrl=1, full masks.
#define DPP_ROR32(dst, src, CTRL) \
    (dst) = (unsigned)__builtin_amdgcn_update_dpp(0, (int)(src), (CTRL), 0xF, 0xF, true)

// async global->LDS, 16B per lane; LDS dest = wave-uniform base + lane*16
__device__ __forceinline__ void gl2lds16(const _Float16* g, _Float16* l) {
    __builtin_amdgcn_global_load_lds(
        (const __attribute__((address_space(1))) unsigned int*)g,
        (__attribute__((address_space(3))) unsigned int*)l, 16, 0, 0);
}

// Pl row c lives in one of three segments (whi-dead, wlo-dead, ws tail)
__device__ __forceinline__ _Float16* plrow(_Float16* p0, _Float16* p1,
                                           _Float16* p2, int c) {
    return c < 1536 ? p0 + (size_t)c * 1536
         : c < 3072 ? p1 + (size_t)(c - 1536) * 1536
                    : p2 + (size_t)(c - 3072) * 1536;
}
__device__ __forceinline__ const _Float16* plrowc(const _Float16* p0,
        const _Float16* p1, const _Float16* p2, int c) {
    return c < 1536 ? p0 + (size_t)c * 1536
         : c < 3072 ? p1 + (size_t)(c - 1536) * 1536
                    : p2 + (size_t)(c - 3072) * 1536;
}

// embed -> ehi/elo halves + esq (fused single pass over embed)
__global__ __launch_bounds__(256) void k_prep_embed(const float* __restrict__ embed,
        _Float16* __restrict__ eh, _Float16* __restrict__ el, float* __restrict__ esq) {
    int c = blockIdx.x * 4 + (threadIdx.x >> 6);    // 1024 blocks
    int lane = threadIdx.x & 63;
    const float* row = embed + (size_t)c * ND + lane * 8;
    float4 v0 = *(const float4*)row;
    float4 v1 = *(const float4*)(row + 4);
    float vs[8] = {v0.x, v0.y, v0.z, v0.w, v1.x, v1.y, v1.z, v1.w};
    half8v h8, l8;
    double acc = 0.0;
#pragma unroll
    for (int i = 0; i < 8; ++i) {
        HL r = split2(vs[i]);
        h8[i] = r.h; l8[i] = r.l;
        acc += (double)vs[i] * (double)vs[i];
    }
    *(half8v*)(eh + (size_t)c * ND + lane * 8) = h8;
    *(half8v*)(el + (size_t)c * ND + lane * 8) = l8;
#pragma unroll
    for (int off = 32; off > 0; off >>= 1) acc += __shfl_down(acc, off, 64);
    if (lane == 0) esq[c] = (float)acc;
}

// Wt2[kp][tap*512+dout][din] hi/lo from pw[kp][dout][din][tap]; output-indexed
__global__ __launch_bounds__(256) void k_split_w(const float* __restrict__ pw,
        _Float16* __restrict__ wh, _Float16* __restrict__ wl) {
    int gid = blockIdx.x * 256 + threadIdx.x;       // 4*1536*512 = 3,145,728
    int din = gid & 511;
    int nn = (gid >> 9) % 1536;
    int kp = gid / (512 * 1536);
    int tap = nn >> 9;
    int dout = nn & 511;
    float v = pw[(((size_t)(kp * 512 + dout) * 512) + din) * 3 + tap];
    HL r = split2(v);
    wh[gid] = r.h;
    wl[gid] = r.l;
}

// z[b,j,d] = block mean of src (fp64 acc) -> split halves zh/zl  (s >= 16)
__global__ __launch_bounds__(256) void k_zmean(const float* __restrict__ src,
        _Float16* __restrict__ zh, _Float16* __restrict__ zl, int s, int lg) {
    int gid = blockIdx.x * 256 + threadIdx.x;       // 16*s*512 threads
    int d = gid & 511;
    int j = (gid >> 9) & (s - 1);
    int b = gid >> (9 + lg);
    int r = 512 >> lg;
    const float* p = src + ((size_t)((b << 9) + (j << (9 - lg))) << 9) + d;
    double acc = 0.0;
#pragma unroll 4
    for (int m = 0; m < r; ++m) acc += (double)p[(size_t)m * ND];
    float v = (float)(acc * (1.0 / (double)r));
    HL hl = split2(v);
    zh[gid] = hl.h;
    zl[gid] = hl.l;
}

// small-s zmean (s <= 8, r = 512/s >= 64): 4-way row-split per 16-lane d-group,
// deterministic shuffle tree ((a0+a2)+(a1+a3)); 8-32x more workgroups.
__global__ __launch_bounds__(256) void k_zmean_s(const float* __restrict__ src,
        _Float16* __restrict__ zh, _Float16* __restrict__ zl, int s, int lg) {
    int bj = blockIdx.x >> 3;          // (b*s + j)
    int dblk = blockIdx.x & 7;
    int b = bj >> lg;
    int j = bj & (s - 1);
    int wave = threadIdx.x >> 6, lane = threadIdx.x & 63;
    int rg = lane >> 4;                // 0..3 row-group
    int dl = lane & 15;
    int d = dblk * 64 + wave * 16 + dl;
    int r = 512 >> lg;
    const float* p = src + ((size_t)((b << 9) + (j << (9 - lg))) << 9) + d;
    double acc = 0.0;
    for (int k = rg; k < r; k += 4) acc += (double)p[(size_t)k * ND];
    acc += __shfl_down(acc, 32, 64);   // rg0+=rg2, rg1+=rg3
    acc += __shfl_down(acc, 16, 64);   // rg0+=rg1'
    if (rg == 0) {
        float v = (float)(acc * (1.0 / (double)r));
        HL hl = split2(v);
        size_t gi = ((size_t)bj << 9) + d;
        zh[gi] = hl.h;
        zl[gi] = hl.l;
    }
}

// ---------------- dist pass 1: hh-only GEMM, 128x128 block, 2x2 waves ----------------
// epilogue: per-(m, half-block) top-2 on u32 keys (payload in low 6 bits),
// DPP row_ror tree; bm2[m][32][2] entries = key<<32 | n. No atomics.
__global__ __launch_bounds__(256, 4) void k_dist1(const _Float16* __restrict__ zh,
        const _Float16* __restrict__ eh, const float* __restrict__ esq,
        unsigned long long* __restrict__ bm2, int M) {
    __shared__ _Float16 smem[2][2][4096] __attribute__((aligned(16)));  // 32 KB
    // epilogue alias (live only after the main loop's trailing barrier): 4 KB
    unsigned long long (*packs2)[2][2] =
        reinterpret_cast<unsigned long long(*)[2][2]>(&smem[0][0][0]);
    int tid = threadIdx.x;
    int lane = tid & 63, wave = tid >> 6;
    int wm = wave >> 1, wn = wave & 1;
    int quad = lane >> 4, l15 = lane & 15;
    int m0 = blockIdx.x * 128, n0 = blockIdx.y * 128;

    int slot = lane & 3;
    int r0 = wave * 32 + (lane >> 2);
    int r1 = r0 + 16;
    int sc0 = (slot ^ ((r0 >> 1) & 3)) << 3;    // swizzled source col (halves)
    int sc1 = (slot ^ ((r1 >> 1) & 3)) << 3;
    int a0 = m0 + r0; if (a0 >= M) a0 = M - 1;
    int a1 = m0 + r1; if (a1 >= M) a1 = M - 1;
    const _Float16* gA0 = zh + (size_t)a0 * 512 + sc0;
    const _Float16* gA1 = zh + (size_t)a1 * 512 + sc1;
    const _Float16* gB0 = eh + (size_t)(n0 + r0) * 512 + sc0;
    const _Float16* gB1 = eh + (size_t)(n0 + r1) * 512 + sc1;
    int ld0 = wave * 1024, ld1 = ld0 + 512;

    int cslot = (quad ^ ((l15 >> 1) & 3)) << 3;
    int rbA = (wm * 64 + l15) * 32 + cslot;
    int rbB = (wn * 64 + l15) * 32 + cslot;

#define STG(buf, kb) do { \
    gl2lds16(gA0 + (kb), &smem[buf][0][ld0]); \
    gl2lds16(gA1 + (kb), &smem[buf][0][ld1]); \
    gl2lds16(gB0 + (kb), &smem[buf][1][ld0]); \
    gl2lds16(gB1 + (kb), &smem[buf][1][ld1]); \
} while (0)

    floatx4 acc[4][4];
#pragma unroll
    for (int i = 0; i < 4; ++i)
#pragma unroll
        for (int j = 0; j < 4; ++j)
#pragma unroll
            for (int r = 0; r < 4; ++r) acc[i][j][r] = 0.f;

    STG(0, 0);
    __syncthreads();
    int cur = 0;
    for (int it = 0; it < 16; ++it) {
        if (it < 15) STG(cur ^ 1, (it + 1) * 32);
        const _Float16* sA = &smem[cur][0][0];
        const _Float16* sB = &smem[cur][1][0];
        half8v af[4], bf[4];
#pragma unroll
        for (int tm = 0; tm < 4; ++tm) af[tm] = *(const half8v*)&sA[rbA + tm * 512];
#pragma unroll
        for (int tn = 0; tn < 4; ++tn) bf[tn] = *(const half8v*)&sB[rbB + tn * 512];
#pragma unroll
        for (int tm = 0; tm < 4; ++tm)
#pragma unroll
            for (int tn = 0; tn < 4; ++tn)
                acc[tm][tn] = __builtin_amdgcn_mfma_f32_16x16x32_f16(af[tm], bf[tn], acc[tm][tn], 0, 0, 0);
        __syncthreads();
        cur ^= 1;
    }
#undef STG
    float es[4];
#pragma unroll
    for (int tn = 0; tn < 4; ++tn) es[tn] = esq[n0 + wn * 64 + tn * 16 + l15];
#pragma unroll
    for (int tm = 0; tm < 4; ++tm)
#pragma unroll
        for (int reg = 0; reg < 4; ++reg) {
            unsigned b = 0xFFFFFFFFu, sd = 0xFFFFFFFFu;
#pragma unroll
            for (int tn = 0; tn < 4; ++tn) {
                float dd = fmaf(-2.f, acc[tm][tn][reg], es[tn]);
                unsigned uu = __float_as_uint(dd);
                uu = (uu & 0x80000000u) ? ~uu : (uu | 0x80000000u);
                unsigned key = (uu & ~63u) | (unsigned)(tn * 16 + l15);
                if (key < b) { sd = b; b = key; } else if (key < sd) sd = key;
            }
            // ror 1,2,4,8: disjoint-coverage top-2 merge over the 16-lane row
            {
                unsigned ob, os, mx, mn2;
                DPP_ROR32(ob, b, 0x121); DPP_ROR32(os, sd, 0x121);
                mx = b > ob ? b : ob; b = b < ob ? b : ob;
                mn2 = sd < os ? sd : os; sd = mx < mn2 ? mx : mn2;
                DPP_ROR32(ob, b, 0x122); DPP_ROR32(os, sd, 0x122);
                mx = b > ob ? b : ob; b = b < ob ? b : ob;
                mn2 = sd < os ? sd : os; sd = mx < mn2 ? mx : mn2;
                DPP_ROR32(ob, b, 0x124); DPP_ROR32(os, sd, 0x124);
                mx = b > ob ? b : ob; b = b < ob ? b : ob;
                mn2 = sd < os ? sd : os; sd = mx < mn2 ? mx : mn2;
                DPP_ROR32(ob, b, 0x128); DPP_ROR32(os, sd, 0x128);
                mx = b > ob ? b : ob; b = b < ob ? b : ob;
                mn2 = sd < os ? sd : os; sd = mx < mn2 ? mx : mn2;
            }
            if (l15 == 0) {
                int base = n0 + wn * 64;
                packs2[wm * 64 + tm * 16 + quad * 4 + reg][wn][0] =
                    ((unsigned long long)b << 32) | (unsigned)(base + (int)(b & 63u));
                packs2[wm * 64 + tm * 16 + quad * 4 + reg][wn][1] =
                    ((unsigned long long)sd << 32) | (unsigned)(base + (int)(sd & 63u));
            }
        }
    __syncthreads();
    if (tid < 128) {
        unsigned long long b0 = packs2[tid][0][0], s0 = packs2[tid][0][1];
        unsigned long long b1 = packs2[tid][1][0], s1 = packs2[tid][1][1];
        unsigned long long b = b0 < b1 ? b0 : b1;
        unsigned long long mx = b0 > b1 ? b0 : b1;
        unsigned long long mn2 = s0 < s1 ? s0 : s1;
        unsigned long long sd = mx < mn2 ? mx : mn2;
        size_t idx = ((size_t)(m0 + tid) * 32 + blockIdx.y) * 2;
        bm2[idx] = b;
        bm2[idx + 1] = sd;
    }
}

// ---------------- dist pass 2: exact refine over 64 gathered candidates ----------------
__global__ __launch_bounds__(256) void k_refine(const _Float16* __restrict__ zh,
        const _Float16* __restrict__ zl, const float* __restrict__ embed,
        const unsigned long long* __restrict__ bm2,
        unsigned long long* __restrict__ minbuf, int M) {
    int lane = threadIdx.x & 63, wave = threadIdx.x >> 6;
    int m = blockIdx.x * 4 + wave;
    if (m >= M) return;
    float zr[8];
    const _Float16* ph = zh + (size_t)m * 512 + lane * 8;
    const _Float16* pl = zl + (size_t)m * 512 + lane * 8;
#pragma unroll
    for (int i = 0; i < 8; ++i)
        zr[i] = (float)ph[i] + (float)pl[i] * (1.0f / 4096.0f);
    unsigned long long p = bm2[(size_t)m * 64 + lane];
    unsigned long long mn = p;
#pragma unroll
    for (int off = 1; off < 64; off <<= 1) {
        unsigned long long q = __shfl_xor(mn, off, 64);
        mn = q < mn ? q : mn;
    }
    float T = unpack_dist(mn) + DELTA;
    unsigned long long mask = __ballot(unpack_dist(p) <= T);
    double bestD = 1e300;
    int bestI = 0x7fffffff;
    while (mask) {
        int bit = __ffsll((unsigned long long)mask) - 1;
        mask &= mask - 1;
        int idx = (int)(unsigned)__shfl(p, bit, 64);
        const float* e = embed + (size_t)idx * 512 + lane * 8;
        double s = 0.0;
#pragma unroll
        for (int i = 0; i < 8; ++i) {
            double df = (double)zr[i] - (double)e[i];
            s += df * df;
        }
#pragma unroll
        for (int off = 32; off > 0; off >>= 1) s += __shfl_down(s, off, 64);
        if (lane == 0) {
            if (s < bestD || (s == bestD && idx < bestI)) { bestD = s; bestI = idx; }
        }
    }
    if (lane == 0) minbuf[m] = (unsigned long long)(unsigned)bestI;
}

// ---------------- phi (8 <= s <= 64): u[m][tap*512+dout] = (W_tap q_m)[dout] ----------------
__global__ __launch_bounds__(256, 2) void k_phi(const _Float16* __restrict__ eh,
        const _Float16* __restrict__ el, const _Float16* __restrict__ wh,
        const _Float16* __restrict__ wl, const unsigned long long* __restrict__ minbuf,
        float* __restrict__ u, int M) {
    __shared__ _Float16 smem[2][4][4096] __attribute__((aligned(16)));  // 64KB exactly
    int* idxs = reinterpret_cast<int*>(&smem[0][0][0]);
    int tid = threadIdx.x;
    int lane = tid & 63, wave = tid >> 6;
    int wm = wave >> 1, wn = wave & 1;
    int quad = lane >> 4, l15 = lane & 15;
    int m0 = blockIdx.x * 128, n0 = blockIdx.y * 128;
    if (tid < 128) {
        int m = m0 + tid; if (m >= M) m = M - 1;
        idxs[tid] = (int)(unsigned)minbuf[m];
    }
    __syncthreads();

    int slot = lane & 3;
    int r0 = wave * 32 + (lane >> 2);
    int r1 = r0 + 16;
    int sc0 = (slot ^ ((r0 >> 1) & 3)) << 3;
    int sc1 = (slot ^ ((r1 >> 1) & 3)) << 3;
    int code0 = idxs[r0];
    int code1 = idxs[r1];
    __syncthreads();   // all waves done reading idxs before DMA overwrites smem
    const _Float16* gA0h = eh + (size_t)code0 * 512 + sc0;
    const _Float16* gA1h = eh + (size_t)code1 * 512 + sc1;
    const _Float16* gA0l = el + (size_t)code0 * 512 + sc0;
    const _Float16* gA1l = el + (size_t)code1 * 512 + sc1;
    const _Float16* gB0h = wh + (size_t)(n0 + r0) * 512 + sc0;
    const _Float16* gB1h = wh + (size_t)(n0 + r1) * 512 + sc1;
    const _Float16* gB0l = wl + (size_t)(n0 + r0) * 512 + sc0;
    const _Float16* gB1l = wl + (size_t)(n0 + r1) * 512 + sc1;
    int ld0 = wave * 1024;
    int ld1 = ld0 + 512;

    int cslot = (quad ^ ((l15 >> 1) & 3)) << 3;
    int rbA = (wm * 64 + l15) * 32 + cslot;
    int rbB = (wn * 64 + l15) * 32 + cslot;

#define STAGE_P(buf, kb) do { \
    gl2lds16(gA0h + (kb), &smem[buf][0][ld0]); \
    gl2lds16(gA1h + (kb), &smem[buf][0][ld1]); \
    gl2lds16(gA0l + (kb), &smem[buf][1][ld0]); \
    gl2lds16(gA1l + (kb), &smem[buf][1][ld1]); \
    gl2lds16(gB0h + (kb), &smem[buf][2][ld0]); \
    gl2lds16(gB1h + (kb), &smem[buf][2][ld1]); \
    gl2lds16(gB0l + (kb), &smem[buf][3][ld0]); \
    gl2lds16(gB1l + (kb), &smem[buf][3][ld1]); \
} while (0)

    floatx4 acch[4][4], accx[4][4];
#pragma unroll
    for (int i = 0; i < 4; ++i)
#pragma unroll
        for (int j = 0; j < 4; ++j)
#pragma unroll
            for (int r = 0; r < 4; ++r) { acch[i][j][r] = 0.f; accx[i][j][r] = 0.f; }

    STAGE_P(0, 0);
    __syncthreads();
    int cur = 0;
    for (int it = 0; it < 16; ++it) {
        if (it < 15) STAGE_P(cur ^ 1, (it + 1) * 32);
        const _Float16* sAh = &smem[cur][0][0];
        const _Float16* sAl = &smem[cur][1][0];
        const _Float16* sBh = &smem[cur][2][0];
        const _Float16* sBl = &smem[cur][3][0];
        half8v afh[4], afl[4], bfh[4], bfl[4];
#pragma unroll
        for (int tm = 0; tm < 4; ++tm) {
            afh[tm] = *(const half8v*)&sAh[rbA + tm * 512];
            afl[tm] = *(const half8v*)&sAl[rbA + tm * 512];
        }
#pragma unroll
        for (int tn = 0; tn < 4; ++tn) {
            bfh[tn] = *(const half8v*)&sBh[rbB + tn * 512];
            bfl[tn] = *(const half8v*)&sBl[rbB + tn * 512];
        }
#pragma unroll
        for (int tm = 0; tm < 4; ++tm)
#pragma unroll
            for (int tn = 0; tn < 4; ++tn) {
                acch[tm][tn] = __builtin_amdgcn_mfma_f32_16x16x32_f16(afh[tm], bfh[tn], acch[tm][tn], 0, 0, 0);
                accx[tm][tn] = __builtin_amdgcn_mfma_f32_16x16x32_f16(afh[tm], bfl[tn], accx[tm][tn], 0, 0, 0);
                accx[tm][tn] = __builtin_amdgcn_mfma_f32_16x16x32_f16(afl[tm], bfh[tn], accx[tm][tn], 0, 0, 0);
            }
        __syncthreads();
        cur ^= 1;
    }
#undef STAGE_P
#pragma unroll
    for (int tm = 0; tm < 4; ++tm)
#pragma unroll
        for (int reg = 0; reg < 4; ++reg) {
            int m = m0 + wm * 64 + tm * 16 + quad * 4 + reg;
            if (m < M) {
#pragma unroll
                for (int tn = 0; tn < 4; ++tn) {
                    int n = n0 + wn * 64 + tn * 16 + l15;
                    u[(size_t)m * 1536 + n] = acch[tm][tn][reg] + accx[tm][tn][reg] * (1.0f / 4096.0f);
                }
            }
        }
}

// small-M phi (s<=4, M<=64): 1 block per m; q row exact f32 in LDS; each
// thread computes 6 outputs as f32 dots over (wh + wl/4096).
__global__ __launch_bounds__(256) void k_phi_s(const float* __restrict__ embed,
        const _Float16* __restrict__ wh, const _Float16* __restrict__ wl,
        const unsigned long long* __restrict__ minbuf, float* __restrict__ u) {
    __shared__ float q[512];
    int m = blockIdx.x;
    int tid = threadIdx.x;
    int code = (int)(unsigned)minbuf[m];
    *(float2*)&q[tid * 2] = *(const float2*)(embed + (size_t)code * 512 + tid * 2);
    __syncthreads();
#pragma unroll
    for (int o = 0; o < 6; ++o) {
        int nn = tid + o * 256;
        const _Float16* wrh = wh + (size_t)nn * 512;
        const _Float16* wrl = wl + (size_t)nn * 512;
        float acc = 0.f;
        for (int k = 0; k < 512; k += 8) {
            half8v h8 = *(const half8v*)(wrh + k);
            half8v l8 = *(const half8v*)(wrl + k);
#pragma unroll
            for (int j = 0; j < 8; ++j)
                acc += q[k + j] * ((float)h8[j] + (float)l8[j] * (1.0f / 4096.0f));
        }
        u[(size_t)m * 1536 + nn] = acc;
    }
}

// ---------------- pmat: P[c][tap*512+dout] = (W3_tap e_c), all 4096 codes ----------------
// k_phi skeleton, identity gather; DUAL-SPLIT output: Ph fp16 + Pl fp16 (x4096).
__global__ __launch_bounds__(256, 2) void k_pmat(const _Float16* __restrict__ eh,
        const _Float16* __restrict__ el, const _Float16* __restrict__ wh,
        const _Float16* __restrict__ wl, _Float16* __restrict__ Ph,
        _Float16* __restrict__ Pl0, _Float16* __restrict__ Pl1,
        _Float16* __restrict__ Pl2) {
    __shared__ _Float16 smem[2][4][4096] __attribute__((aligned(16)));  // 64KB
    int tid = threadIdx.x;
    int lane = tid & 63, wave = tid >> 6;
    int wm = wave >> 1, wn = wave & 1;
    int quad = lane >> 4, l15 = lane & 15;
    int m0 = blockIdx.x * 128, n0 = blockIdx.y * 128;

    int slot = lane & 3;
    int r0 = wave * 32 + (lane >> 2);
    int r1 = r0 + 16;
    int sc0 = (slot ^ ((r0 >> 1) & 3)) << 3;
    int sc1 = (slot ^ ((r1 >> 1) & 3)) << 3;
    int code0 = m0 + r0;   // identity gather
    int code1 = m0 + r1;
    const _Float16* gA0h = eh + (size_t)code0 * 512 + sc0;
    const _Float16* gA1h = eh + (size_t)code1 * 512 + sc1;
    const _Float16* gA0l = el + (size_t)code0 * 512 + sc0;
    const _Float16* gA1l = el + (size_t)code1 * 512 + sc1;
    const _Float16* gB0h = wh + (size_t)(n0 + r0) * 512 + sc0;
    const _Float16* gB1h = wh + (size_t)(n0 + r1) * 512 + sc1;
    const _Float16* gB0l = wl + (size_t)(n0 + r0) * 512 + sc0;
    const _Float16* gB1l = wl + (size_t)(n0 + r1) * 512 + sc1;
    int ld0 = wave * 1024;
    int ld1 = ld0 + 512;

    int cslot = (quad ^ ((l15 >> 1) & 3)) << 3;
    int rbA = (wm * 64 + l15) * 32 + cslot;
    int rbB = (wn * 64 + l15) * 32 + cslot;

#define STAGE_M(buf, kb) do { \
    gl2lds16(gA0h + (kb), &smem[buf][0][ld0]); \
    gl2lds16(gA1h + (kb), &smem[buf][0][ld1]); \
    gl2lds16(gA0l + (kb), &smem[buf][1][ld0]); \
    gl2lds16(gA1l + (kb), &smem[buf][1][ld1]); \
    gl2lds16(gB0h + (kb), &smem[buf][2][ld0]); \
    gl2lds16(gB1h + (kb), &smem[buf][2][ld1]); \
    gl2lds16(gB0l + (kb), &smem[buf][3][ld0]); \
    gl2lds16(gB1l + (kb), &smem[buf][3][ld1]); \
} while (0)

    floatx4 acch[4][4], accx[4][4];
#pragma unroll
    for (int i = 0; i < 4; ++i)
#pragma unroll
        for (int j = 0; j < 4; ++j)
#pragma unroll
            for (int r = 0; r < 4; ++r) { acch[i][j][r] = 0.f; accx[i][j][r] = 0.f; }

    STAGE_M(0, 0);
    __syncthreads();
    int cur = 0;
    for (int it = 0; it < 16; ++it) {
        if (it < 15) STAGE_M(cur ^ 1, (it + 1) * 32);
        const _Float16* sAh = &smem[cur][0][0];
        const _Float16* sAl = &smem[cur][1][0];
        const _Float16* sBh = &smem[cur][2][0];
        const _Float16* sBl = &smem[cur][3][0];
        half8v afh[4], afl[4], bfh[4], bfl[4];
#pragma unroll
        for (int tm = 0; tm < 4; ++tm) {
            afh[tm] = *(const half8v*)&sAh[rbA + tm * 512];
            afl[tm] = *(const half8v*)&sAl[rbA + tm * 512];
        }
#pragma unroll
        for (int tn = 0; tn < 4; ++tn) {
            bfh[tn] = *(const half8v*)&sBh[rbB + tn * 512];
            bfl[tn] = *(const half8v*)&sBl[rbB + tn * 512];
        }
#pragma unroll
        for (int tm = 0; tm < 4; ++tm)
#pragma unroll
            for (int tn = 0; tn < 4; ++tn) {
                acch[tm][tn] = __builtin_amdgcn_mfma_f32_16x16x32_f16(afh[tm], bfh[tn], acch[tm][tn], 0, 0, 0);
                accx[tm][tn] = __builtin_amdgcn_mfma_f32_16x16x32_f16(afh[tm], bfl[tn], accx[tm][tn], 0, 0, 0);
                accx[tm][tn] = __builtin_amdgcn_mfma_f32_16x16x32_f16(afl[tm], bfh[tn], accx[tm][tn], 0, 0, 0);
            }
        __syncthreads();
        cur ^= 1;
    }
#undef STAGE_M
#pragma unroll
    for (int tm = 0; tm < 4; ++tm)
#pragma unroll
        for (int reg = 0; reg < 4; ++reg) {
            int m = m0 + wm * 64 + tm * 16 + quad * 4 + reg;
            _Float16* plr = plrow(Pl0, Pl1, Pl2, m);
#pragma unroll
            for (int tn = 0; tn < 4; ++tn) {
                int n = n0 + wn * 64 + tn * 16 + l15;
                float val = acch[tm][tn][reg] + accx[tm][tn][reg] * (1.0f / 4096.0f);
                HL r = split2(val);
                Ph[(size_t)m * 1536 + n] = r.h;
                plr[n] = r.l;
            }
        }
}

// combine (s<=64, u-path): resid = rsrc - (0.5*h + 0.5*(conv+bias))
__global__ __launch_bounds__(256) void k_combine(const float* __restrict__ u,
        const float* __restrict__ embed, const unsigned long long* __restrict__ minbuf,
        const float* __restrict__ bias, const float* __restrict__ rsrc,
        float* __restrict__ resid, int s, float scale) {
    int tid = threadIdx.x;
    int m = blockIdx.x * 2 + (tid >> 7);
    int d4 = (tid & 127) << 2;
    int b = m >> 9, t = m & 511;
    int bs = b * s;
    float4 bi = *(const float4*)(bias + d4);
    float uu = ((float)t + 0.5f) * scale - 0.5f;
    float fl = floorf(uu);
    float w = uu - fl;
    int i0 = (int)fl, i1 = i0 + 1;
    i0 = min(max(i0, 0), s - 1);
    i1 = min(max(i1, 0), s - 1);
    int c0 = (int)(unsigned)minbuf[bs + i0];
    int c1 = (int)(unsigned)minbuf[bs + i1];
    float4 e0 = *(const float4*)(embed + (size_t)c0 * 512 + d4);
    float4 e1 = *(const float4*)(embed + (size_t)c1 * 512 + d4);
    float om = 1.0f - w;
    float4 h4;
    h4.x = om * e0.x + w * e1.x; h4.y = om * e0.y + w * e1.y;
    h4.z = om * e0.z + w * e1.z; h4.w = om * e0.w + w * e1.w;
    float4 conv = make_float4(0.f, 0.f, 0.f, 0.f);
#pragma unroll
    for (int tap = 0; tap < 3; ++tap) {
        int tt = t + tap - 1;
        if (tt >= 0 && tt < 512) {
            float uu2 = ((float)tt + 0.5f) * scale - 0.5f;
            float fl2 = floorf(uu2);
            float w2 = uu2 - fl2;
            int j0 = (int)fl2, j1 = j0 + 1;
            j0 = min(max(j0, 0), s - 1);
            j1 = min(max(j1, 0), s - 1);
            float4 a4 = *(const float4*)(u + (size_t)(bs + j0) * 1536 + tap * 512 + d4);
            float4 b4 = *(const float4*)(u + (size_t)(bs + j1) * 1536 + tap * 512 + d4);
            float ow = 1.0f - w2;
            conv.x += ow * a4.x + w2 * b4.x;
            conv.y += ow * a4.y + w2 * b4.y;
            conv.z += ow * a4.z + w2 * b4.z;
            conv.w += ow * a4.w + w2 * b4.w;
        }
    }
    size_t off = (size_t)m * 512 + d4;
    float4 rv = *(const float4*)(rsrc + off);
    rv.x -= 0.5f * h4.x + 0.5f * (conv.x + bi.x);
    rv.y -= 0.5f * h4.y + 0.5f * (conv.y + bi.y);
    rv.z -= 0.5f * h4.z + 0.5f * (conv.z + bi.z);
    rv.w -= 0.5f * h4.w + 0.5f * (conv.w + bi.w);
    *(float4*)(resid + off) = rv;
}

// combineP (s in {128,256,512}): conv via code-indexed dual-split P lerps.
// resid = rsrc - (0.5*h + 0.5*(conv+bias)); s==512 -> w2==0, single gather.
__global__ __launch_bounds__(256) void k_combineP(const _Float16* __restrict__ Ph,
        const _Float16* __restrict__ Pl0, const _Float16* __restrict__ Pl1,
        const _Float16* __restrict__ Pl2,
        const float* __restrict__ embed, const unsigned long long* __restrict__ minbuf,
        const float* __restrict__ bias, const float* __restrict__ rsrc,
        float* __restrict__ resid, int s, float scale) {
    int tid = threadIdx.x;
    int m = blockIdx.x * 2 + (tid >> 7);
    int d4 = (tid & 127) << 2;
    int b = m >> 9, t = m & 511;
    int bs = b * s;
    int noint = (s == 512);
    float4 bi = *(const float4*)(bias + d4);
    float uu = ((float)t + 0.5f) * scale - 0.5f;
    float fl = floorf(uu);
    float w = uu - fl;
    int i0 = (int)fl, i1 = i0 + 1;
    i0 = min(max(i0, 0), s - 1);
    i1 = min(max(i1, 0), s - 1);
    int c0 = (int)(unsigned)minbuf[bs + i0];
    int c1 = (int)(unsigned)minbuf[bs + i1];
    float4 e0 = *(const float4*)(embed + (size_t)c0 * 512 + d4);
    float4 e1 = *(const float4*)(embed + (size_t)c1 * 512 + d4);
    float om = 1.0f - w;
    float4 h4;
    h4.x = om * e0.x + w * e1.x; h4.y = om * e0.y + w * e1.y;
    h4.z = om * e0.z + w * e1.z; h4.w = om * e0.w + w * e1.w;
    float4 conv = make_float4(0.f, 0.f, 0.f, 0.f);
#pragma unroll
    for (int tap = 0; tap < 3; ++tap) {
        int tt = t + tap - 1;
        if (tt >= 0 && tt < 512) {
            float uu2 = ((float)tt + 0.5f) * scale - 0.5f;
            float fl2 = floorf(uu2);
            float w2 = uu2 - fl2;
            int j0 = (int)fl2, j1 = j0 + 1;
            j0 = min(max(j0, 0), s - 1);
            j1 = min(max(j1, 0), s - 1);
            int cc0 = (int)(unsigned)minbuf[bs + j0];
            size_t oseg = tap * 512 + d4;
            half4v ah = *(const half4v*)(Ph + (size_t)cc0 * 1536 + oseg);
            half4v al = *(const half4v*)(plrowc(Pl0, Pl1, Pl2, cc0) + oseg);
            if (noint) {
                // w2 == 0 exactly: conv += av
#pragma unroll
                for (int q = 0; q < 4; ++q) {
                    float av = (float)ah[q] + (float)al[q] * (1.0f / 4096.0f);
                    float* cp = q == 0 ? &conv.x : q == 1 ? &conv.y : q == 2 ? &conv.z : &conv.w;
                    *cp += av;
                }
            } else {
                int cc1 = (int)(unsigned)minbuf[bs + j1];
                half4v bh = *(const half4v*)(Ph + (size_t)cc1 * 1536 + oseg);
                half4v bl = *(const half4v*)(plrowc(Pl0, Pl1, Pl2, cc1) + oseg);
                float ow = 1.0f - w2;
#pragma unroll
                for (int q = 0; q < 4; ++q) {
                    float av = (float)ah[q] + (float)al[q] * (1.0f / 4096.0f);
                    float bv = (float)bh[q] + (float)bl[q] * (1.0f / 4096.0f);
                    float* cp = q == 0 ? &conv.x : q == 1 ? &conv.y : q == 2 ? &conv.z : &conv.w;
                    *cp += ow * av + w2 * bv;
                }
            }
        }
    }
    size_t off = (size_t)m * 512 + d4;
    float4 rv = *(const float4*)(rsrc + off);
    rv.x -= 0.5f * h4.x + 0.5f * (conv.x + bi.x);
    rv.y -= 0.5f * h4.y + 0.5f * (conv.y + bi.y);
    rv.z -= 0.5f * h4.z + 0.5f * (conv.z + bi.z);
    rv.w -= 0.5f * h4.w + 0.5f * (conv.w + bi.w);
    *(float4*)(resid + off) = rv;
}

__global__ __launch_bounds__(256) void k_final(const float* __restrict__ x,
        const float* __restrict__ resid, float* __restrict__ out) {
    int gid = blockIdx.x * 256 + threadIdx.x;
    float4 xv = ((const float4*)x)[gid];
    float4 rv = ((const float4*)resid)[gid];
    float4 o;
    o.x = xv.x - rv.x; o.y = xv.y - rv.y; o.z = xv.z - rv.z; o.w = xv.w - rv.w;
    ((float4*)out)[gid] = o;
}

extern "C" void kernel_launch(void* const* d_in, const int* in_sizes, int n_in,
                              void* d_out, int out_size, void* d_ws, size_t ws_size,
                              hipStream_t stream) {
    const float* x     = (const float*)d_in[0];
    const float* embed = (const float*)d_in[1];
    const float* pw    = (const float*)d_in[2];
    const float* pb    = (const float*)d_in[3];
    float* out = (float*)d_out;

    // ws layout (floats), ~59.1 MB:
    // resid 16MB | U 16MB (zh/zl; u aliases, s<=64) | ehi/elo 8MB |
    // Wt2 hi/lo 12MB (kp0-2 rows reused as Pl segs after si=6) |
    // esq 16KB | minbuf 64KB | bm2 4MB | Pl tail 3MB
    // Ph (fp16, 12.6MB) lives in d_out (out written only by k_final).
    float* resid = (float*)d_ws;
    float* Ubase = resid + 4194304;
    _Float16* zh = (_Float16*)Ubase;
    _Float16* zl = zh + 4194304;
    float* u = Ubase;
    _Float16* ehi = (_Float16*)(Ubase + 4194304);
    _Float16* elo = ehi + 2097152;
    _Float16* whi = elo + 2097152;
    _Float16* wlo = whi + 3145728;
    float* esq = (float*)(wlo + 3145728);
    unsigned long long* minbuf = (unsigned long long*)(esq + 4096);
    unsigned long long* bm2 = (unsigned long long*)(minbuf + 8192);
    _Float16* Ph = (_Float16*)d_out;
    _Float16* Pl0 = whi;                        // rows 0..1535   (dead kp0-2)
    _Float16* Pl1 = wlo;                        // rows 1536..3071 (dead kp0-2)
    _Float16* Pl2 = (_Float16*)(bm2 + 524288);  // rows 3072..4095 (3MB tail)

    k_prep_embed<<<1024, 256, 0, stream>>>(embed, ehi, elo, esq);
    k_split_w<<<12288, 256, 0, stream>>>(pw, whi, wlo);

    const int SCv[10] = {1, 2, 4, 8, 16, 32, 64, 128, 256, 512};
    // PHI_IDX with float64-ulp tie-breaks at si=2 and si=7 (verified round 2)
    const int PIv[10] = {0, 0, 1, 1, 1, 2, 2, 3, 3, 3};
    for (int si = 0; si < 10; ++si) {
        int s = SCv[si];
        int M = 16 * s;
        int kp = PIv[si];
        int lg = __builtin_ctz((unsigned)s);
        float scale = (float)s / 512.0f;
        const float* src = (si == 0) ? x : resid;
        if (s <= 8)
            k_zmean_s<<<16 * s * 8, 256, 0, stream>>>(src, zh, zl, s, lg);
        else
            k_zmean<<<(M * 512) / 256, 256, 0, stream>>>(src, zh, zl, s, lg);
        k_dist1<<<dim3((M + 127) / 128, 32), 256, 0, stream>>>(zh, ehi, esq, bm2, M);
        k_refine<<<(M + 3) / 4, 256, 0, stream>>>(zh, zl, embed, bm2, minbuf, M);
        if (si <= 6) {
            if (s <= 4)
                k_phi_s<<<M, 256, 0, stream>>>(embed,
                        whi + (size_t)kp * 1536 * 512, wlo + (size_t)kp * 1536 * 512, minbuf, u);
            else
                k_phi<<<dim3((M + 127) / 128, 12), 256, 0, stream>>>(ehi, elo,
                        whi + (size_t)kp * 1536 * 512, wlo + (size_t)kp * 1536 * 512, minbuf, u, M);
            k_combine<<<4096, 256, 0, stream>>>(u, embed, minbuf, pb + kp * 512, src, resid, s, scale);
        } else {
            if (si == 7)
                k_pmat<<<dim3(32, 12), 256, 0, stream>>>(ehi, elo,
                        whi + (size_t)3 * 1536 * 512, wlo + (size_t)3 * 1536 * 512,
                        Ph, Pl0, Pl1, Pl2);
            k_combineP<<<4096, 256, 0, stream>>>(Ph, Pl0, Pl1, Pl2, embed, minbuf,
                    pb + 3 * 512, src, resid, s, scale);
        }
    }
    k_final<<<4096, 256, 0, stream>>>(x, resid, out);
}

// Round 13
// 683.534 us; speedup vs baseline: 1.3541x; 1.3541x over previous
//
#include <hip/hip_runtime.h>

// Multiscale Residual VQ (VAR-style), MI355X gfx950.
// Round 18 = Round 17 minus k_phi_s (which was 103us x3: 16 blocks on 256
// CUs, 0.7% occupancy, BW-serialized weight streaming - strictly worse than
// the 12-block MFMA k_phi it replaced). All si<=6 go through k_phi again.
// Keeps round 17's u32-key DPP top-2 epilogue in k_dist1 (payload in low 6
// mantissa bits; perturbation ~0.008 << DELTA=0.5; deterministic) and the
// s==512 single-gather fast path in k_combineP.

#define ND 512
#define NCB 4096
#define DELTA 0.5f

typedef _Float16 half8v __attribute__((ext_vector_type(8)));
typedef _Float16 half4v __attribute__((ext_vector_type(4)));
typedef float floatx4 __attribute__((ext_vector_type(4)));

struct HL { _Float16 h, l; };

__device__ __forceinline__ HL split2(float v) {
    HL r;
    r.h = (_Float16)v;
    r.l = (_Float16)((v - (float)r.h) * 4096.0f);
    return r;
}

__device__ __forceinline__ unsigned long long pack_dist(float d, int n) {
    unsigned u = __float_as_uint(d);
    u = (u & 0x80000000u) ? ~u : (u | 0x80000000u);   // monotone total order
    return ((unsigned long long)u << 32) | (unsigned)n; // tie -> lowest idx
}

__device__ __forceinline__ float unpack_dist(unsigned long long p) {
    unsigned u = (unsigned)(p >> 32);
    u = (u & 0x80000000u) ? (u & 0x7fffffffu) : ~u;
    return __uint_as_float(u);
}

// u32 DPP row_ror move (ctrl literal); bound_ctrl=1, full masks.
#define DPP_ROR32(dst, src, CTRL) \
    (dst) = (unsigned)__builtin_amdgcn_update_dpp(0, (int)(src), (CTRL), 0xF, 0xF, true)

// async global->LDS, 16B per lane; LDS dest = wave-uniform base + lane*16
__device__ __forceinline__ void gl2lds16(const _Float16* g, _Float16* l) {
    __builtin_amdgcn_global_load_lds(
        (const __attribute__((address_space(1))) unsigned int*)g,
        (__attribute__((address_space(3))) unsigned int*)l, 16, 0, 0);
}

// Pl row c lives in one of three segments (whi-dead, wlo-dead, ws tail)
__device__ __forceinline__ _Float16* plrow(_Float16* p0, _Float16* p1,
                                           _Float16* p2, int c) {
    return c < 1536 ? p0 + (size_t)c * 1536
         : c < 3072 ? p1 + (size_t)(c - 1536) * 1536
                    : p2 + (size_t)(c - 3072) * 1536;
}
__device__ __forceinline__ const _Float16* plrowc(const _Float16* p0,
        const _Float16* p1, const _Float16* p2, int c) {
    return c < 1536 ? p0 + (size_t)c * 1536
         : c < 3072 ? p1 + (size_t)(c - 1536) * 1536
                    : p2 + (size_t)(c - 3072) * 1536;
}

// embed -> ehi/elo halves + esq (fused single pass over embed)
__global__ __launch_bounds__(256) void k_prep_embed(const float* __restrict__ embed,
        _Float16* __restrict__ eh, _Float16* __restrict__ el, float* __restrict__ esq) {
    int c = blockIdx.x * 4 + (threadIdx.x >> 6);    // 1024 blocks
    int lane = threadIdx.x & 63;
    const float* row = embed + (size_t)c * ND + lane * 8;
    float4 v0 = *(const float4*)row;
    float4 v1 = *(const float4*)(row + 4);
    float vs[8] = {v0.x, v0.y, v0.z, v0.w, v1.x, v1.y, v1.z, v1.w};
    half8v h8, l8;
    double acc = 0.0;
#pragma unroll
    for (int i = 0; i < 8; ++i) {
        HL r = split2(vs[i]);
        h8[i] = r.h; l8[i] = r.l;
        acc += (double)vs[i] * (double)vs[i];
    }
    *(half8v*)(eh + (size_t)c * ND + lane * 8) = h8;
    *(half8v*)(el + (size_t)c * ND + lane * 8) = l8;
#pragma unroll
    for (int off = 32; off > 0; off >>= 1) acc += __shfl_down(acc, off, 64);
    if (lane == 0) esq[c] = (float)acc;
}

// Wt2[kp][tap*512+dout][din] hi/lo from pw[kp][dout][din][tap]; output-indexed
__global__ __launch_bounds__(256) void k_split_w(const float* __restrict__ pw,
        _Float16* __restrict__ wh, _Float16* __restrict__ wl) {
    int gid = blockIdx.x * 256 + threadIdx.x;       // 4*1536*512 = 3,145,728
    int din = gid & 511;
    int nn = (gid >> 9) % 1536;
    int kp = gid / (512 * 1536);
    int tap = nn >> 9;
    int dout = nn & 511;
    float v = pw[(((size_t)(kp * 512 + dout) * 512) + din) * 3 + tap];
    HL r = split2(v);
    wh[gid] = r.h;
    wl[gid] = r.l;
}

// z[b,j,d] = block mean of src (fp64 acc) -> split halves zh/zl  (s >= 16)
__global__ __launch_bounds__(256) void k_zmean(const float* __restrict__ src,
        _Float16* __restrict__ zh, _Float16* __restrict__ zl, int s, int lg) {
    int gid = blockIdx.x * 256 + threadIdx.x;       // 16*s*512 threads
    int d = gid & 511;
    int j = (gid >> 9) & (s - 1);
    int b = gid >> (9 + lg);
    int r = 512 >> lg;
    const float* p = src + ((size_t)((b << 9) + (j << (9 - lg))) << 9) + d;
    double acc = 0.0;
#pragma unroll 4
    for (int m = 0; m < r; ++m) acc += (double)p[(size_t)m * ND];
    float v = (float)(acc * (1.0 / (double)r));
    HL hl = split2(v);
    zh[gid] = hl.h;
    zl[gid] = hl.l;
}

// small-s zmean (s <= 8, r = 512/s >= 64): 4-way row-split per 16-lane d-group,
// deterministic shuffle tree ((a0+a2)+(a1+a3)); 8-32x more workgroups.
__global__ __launch_bounds__(256) void k_zmean_s(const float* __restrict__ src,
        _Float16* __restrict__ zh, _Float16* __restrict__ zl, int s, int lg) {
    int bj = blockIdx.x >> 3;          // (b*s + j)
    int dblk = blockIdx.x & 7;
    int b = bj >> lg;
    int j = bj & (s - 1);
    int wave = threadIdx.x >> 6, lane = threadIdx.x & 63;
    int rg = lane >> 4;                // 0..3 row-group
    int dl = lane & 15;
    int d = dblk * 64 + wave * 16 + dl;
    int r = 512 >> lg;
    const float* p = src + ((size_t)((b << 9) + (j << (9 - lg))) << 9) + d;
    double acc = 0.0;
    for (int k = rg; k < r; k += 4) acc += (double)p[(size_t)k * ND];
    acc += __shfl_down(acc, 32, 64);   // rg0+=rg2, rg1+=rg3
    acc += __shfl_down(acc, 16, 64);   // rg0+=rg1'
    if (rg == 0) {
        float v = (float)(acc * (1.0 / (double)r));
        HL hl = split2(v);
        size_t gi = ((size_t)bj << 9) + d;
        zh[gi] = hl.h;
        zl[gi] = hl.l;
    }
}

// ---------------- dist pass 1: hh-only GEMM, 128x128 block, 2x2 waves ----------------
// epilogue: per-(m, half-block) top-2 on u32 keys (payload in low 6 bits),
// DPP row_ror tree; bm2[m][32][2] entries = key<<32 | n. No atomics.
__global__ __launch_bounds__(256, 4) void k_dist1(const _Float16* __restrict__ zh,
        const _Float16* __restrict__ eh, const float* __restrict__ esq,
        unsigned long long* __restrict__ bm2, int M) {
    __shared__ _Float16 smem[2][2][4096] __attribute__((aligned(16)));  // 32 KB
    // epilogue alias (live only after the main loop's trailing barrier): 4 KB
    unsigned long long (*packs2)[2][2] =
        reinterpret_cast<unsigned long long(*)[2][2]>(&smem[0][0][0]);
    int tid = threadIdx.x;
    int lane = tid & 63, wave = tid >> 6;
    int wm = wave >> 1, wn = wave & 1;
    int quad = lane >> 4, l15 = lane & 15;
    int m0 = blockIdx.x * 128, n0 = blockIdx.y * 128;

    int slot = lane & 3;
    int r0 = wave * 32 + (lane >> 2);
    int r1 = r0 + 16;
    int sc0 = (slot ^ ((r0 >> 1) & 3)) << 3;    // swizzled source col (halves)
    int sc1 = (slot ^ ((r1 >> 1) & 3)) << 3;
    int a0 = m0 + r0; if (a0 >= M) a0 = M - 1;
    int a1 = m0 + r1; if (a1 >= M) a1 = M - 1;
    const _Float16* gA0 = zh + (size_t)a0 * 512 + sc0;
    const _Float16* gA1 = zh + (size_t)a1 * 512 + sc1;
    const _Float16* gB0 = eh + (size_t)(n0 + r0) * 512 + sc0;
    const _Float16* gB1 = eh + (size_t)(n0 + r1) * 512 + sc1;
    int ld0 = wave * 1024, ld1 = ld0 + 512;

    int cslot = (quad ^ ((l15 >> 1) & 3)) << 3;
    int rbA = (wm * 64 + l15) * 32 + cslot;
    int rbB = (wn * 64 + l15) * 32 + cslot;

#define STG(buf, kb) do { \
    gl2lds16(gA0 + (kb), &smem[buf][0][ld0]); \
    gl2lds16(gA1 + (kb), &smem[buf][0][ld1]); \
    gl2lds16(gB0 + (kb), &smem[buf][1][ld0]); \
    gl2lds16(gB1 + (kb), &smem[buf][1][ld1]); \
} while (0)

    floatx4 acc[4][4];
#pragma unroll
    for (int i = 0; i < 4; ++i)
#pragma unroll
        for (int j = 0; j < 4; ++j)
#pragma unroll
            for (int r = 0; r < 4; ++r) acc[i][j][r] = 0.f;

    STG(0, 0);
    __syncthreads();
    int cur = 0;
    for (int it = 0; it < 16; ++it) {
        if (it < 15) STG(cur ^ 1, (it + 1) * 32);
        const _Float16* sA = &smem[cur][0][0];
        const _Float16* sB = &smem[cur][1][0];
        half8v af[4], bf[4];
#pragma unroll
        for (int tm = 0; tm < 4; ++tm) af[tm] = *(const half8v*)&sA[rbA + tm * 512];
#pragma unroll
        for (int tn = 0; tn < 4; ++tn) bf[tn] = *(const half8v*)&sB[rbB + tn * 512];
#pragma unroll
        for (int tm = 0; tm < 4; ++tm)
#pragma unroll
            for (int tn = 0; tn < 4; ++tn)
                acc[tm][tn] = __builtin_amdgcn_mfma_f32_16x16x32_f16(af[tm], bf[tn], acc[tm][tn], 0, 0, 0);
        __syncthreads();
        cur ^= 1;
    }
#undef STG
    float es[4];
#pragma unroll
    for (int tn = 0; tn < 4; ++tn) es[tn] = esq[n0 + wn * 64 + tn * 16 + l15];
#pragma unroll
    for (int tm = 0; tm < 4; ++tm)
#pragma unroll
        for (int reg = 0; reg < 4; ++reg) {
            unsigned b = 0xFFFFFFFFu, sd = 0xFFFFFFFFu;
#pragma unroll
            for (int tn = 0; tn < 4; ++tn) {
                float dd = fmaf(-2.f, acc[tm][tn][reg], es[tn]);
                unsigned uu = __float_as_uint(dd);
                uu = (uu & 0x80000000u) ? ~uu : (uu | 0x80000000u);
                unsigned key = (uu & ~63u) | (unsigned)(tn * 16 + l15);
                if (key < b) { sd = b; b = key; } else if (key < sd) sd = key;
            }
            // ror 1,2,4,8: disjoint-coverage top-2 merge over the 16-lane row
            {
                unsigned ob, os, mx, mn2;
                DPP_ROR32(ob, b, 0x121); DPP_ROR32(os, sd, 0x121);
                mx = b > ob ? b : ob; b = b < ob ? b : ob;
                mn2 = sd < os ? sd : os; sd = mx < mn2 ? mx : mn2;
                DPP_ROR32(ob, b, 0x122); DPP_ROR32(os, sd, 0x122);
                mx = b > ob ? b : ob; b = b < ob ? b : ob;
                mn2 = sd < os ? sd : os; sd = mx < mn2 ? mx : mn2;
                DPP_ROR32(ob, b, 0x124); DPP_ROR32(os, sd, 0x124);
                mx = b > ob ? b : ob; b = b < ob ? b : ob;
                mn2 = sd < os ? sd : os; sd = mx < mn2 ? mx : mn2;
                DPP_ROR32(ob, b, 0x128); DPP_ROR32(os, sd, 0x128);
                mx = b > ob ? b : ob; b = b < ob ? b : ob;
                mn2 = sd < os ? sd : os; sd = mx < mn2 ? mx : mn2;
            }
            if (l15 == 0) {
                int base = n0 + wn * 64;
                packs2[wm * 64 + tm * 16 + quad * 4 + reg][wn][0] =
                    ((unsigned long long)b << 32) | (unsigned)(base + (int)(b & 63u));
                packs2[wm * 64 + tm * 16 + quad * 4 + reg][wn][1] =
                    ((unsigned long long)sd << 32) | (unsigned)(base + (int)(sd & 63u));
            }
        }
    __syncthreads();
    if (tid < 128) {
        unsigned long long b0 = packs2[tid][0][0], s0 = packs2[tid][0][1];
        unsigned long long b1 = packs2[tid][1][0], s1 = packs2[tid][1][1];
        unsigned long long b = b0 < b1 ? b0 : b1;
        unsigned long long mx = b0 > b1 ? b0 : b1;
        unsigned long long mn2 = s0 < s1 ? s0 : s1;
        unsigned long long sd = mx < mn2 ? mx : mn2;
        size_t idx = ((size_t)(m0 + tid) * 32 + blockIdx.y) * 2;
        bm2[idx] = b;
        bm2[idx + 1] = sd;
    }
}

// ---------------- dist pass 2: exact refine over 64 gathered candidates ----------------
__global__ __launch_bounds__(256) void k_refine(const _Float16* __restrict__ zh,
        const _Float16* __restrict__ zl, const float* __restrict__ embed,
        const unsigned long long* __restrict__ bm2,
        unsigned long long* __restrict__ minbuf, int M) {
    int lane = threadIdx.x & 63, wave = threadIdx.x >> 6;
    int m = blockIdx.x * 4 + wave;
    if (m >= M) return;
    float zr[8];
    const _Float16* ph = zh + (size_t)m * 512 + lane * 8;
    const _Float16* pl = zl + (size_t)m * 512 + lane * 8;
#pragma unroll
    for (int i = 0; i < 8; ++i)
        zr[i] = (float)ph[i] + (float)pl[i] * (1.0f / 4096.0f);
    unsigned long long p = bm2[(size_t)m * 64 + lane];
    unsigned long long mn = p;
#pragma unroll
    for (int off = 1; off < 64; off <<= 1) {
        unsigned long long q = __shfl_xor(mn, off, 64);
        mn = q < mn ? q : mn;
    }
    float T = unpack_dist(mn) + DELTA;
    unsigned long long mask = __ballot(unpack_dist(p) <= T);
    double bestD = 1e300;
    int bestI = 0x7fffffff;
    while (mask) {
        int bit = __ffsll((unsigned long long)mask) - 1;
        mask &= mask - 1;
        int idx = (int)(unsigned)__shfl(p, bit, 64);
        const float* e = embed + (size_t)idx * 512 + lane * 8;
        double s = 0.0;
#pragma unroll
        for (int i = 0; i < 8; ++i) {
            double df = (double)zr[i] - (double)e[i];
            s += df * df;
        }
#pragma unroll
        for (int off = 32; off > 0; off >>= 1) s += __shfl_down(s, off, 64);
        if (lane == 0) {
            if (s < bestD || (s == bestD && idx < bestI)) { bestD = s; bestI = idx; }
        }
    }
    if (lane == 0) minbuf[m] = (unsigned long long)(unsigned)bestI;
}

// ---------------- phi (s<=64): u[m][tap*512+dout] = (W_tap q_m)[dout] ----------------
__global__ __launch_bounds__(256, 2) void k_phi(const _Float16* __restrict__ eh,
        const _Float16* __restrict__ el, const _Float16* __restrict__ wh,
        const _Float16* __restrict__ wl, const unsigned long long* __restrict__ minbuf,
        float* __restrict__ u, int M) {
    __shared__ _Float16 smem[2][4][4096] __attribute__((aligned(16)));  // 64KB exactly
    int* idxs = reinterpret_cast<int*>(&smem[0][0][0]);
    int tid = threadIdx.x;
    int lane = tid & 63, wave = tid >> 6;
    int wm = wave >> 1, wn = wave & 1;
    int quad = lane >> 4, l15 = lane & 15;
    int m0 = blockIdx.x * 128, n0 = blockIdx.y * 128;
    if (tid < 128) {
        int m = m0 + tid; if (m >= M) m = M - 1;
        idxs[tid] = (int)(unsigned)minbuf[m];
    }
    __syncthreads();

    int slot = lane & 3;
    int r0 = wave * 32 + (lane >> 2);
    int r1 = r0 + 16;
    int sc0 = (slot ^ ((r0 >> 1) & 3)) << 3;
    int sc1 = (slot ^ ((r1 >> 1) & 3)) << 3;
    int code0 = idxs[r0];
    int code1 = idxs[r1];
    __syncthreads();   // all waves done reading idxs before DMA overwrites smem
    const _Float16* gA0h = eh + (size_t)code0 * 512 + sc0;
    const _Float16* gA1h = eh + (size_t)code1 * 512 + sc1;
    const _Float16* gA0l = el + (size_t)code0 * 512 + sc0;
    const _Float16* gA1l = el + (size_t)code1 * 512 + sc1;
    const _Float16* gB0h = wh + (size_t)(n0 + r0) * 512 + sc0;
    const _Float16* gB1h = wh + (size_t)(n0 + r1) * 512 + sc1;
    const _Float16* gB0l = wl + (size_t)(n0 + r0) * 512 + sc0;
    const _Float16* gB1l = wl + (size_t)(n0 + r1) * 512 + sc1;
    int ld0 = wave * 1024;
    int ld1 = ld0 + 512;

    int cslot = (quad ^ ((l15 >> 1) & 3)) << 3;
    int rbA = (wm * 64 + l15) * 32 + cslot;
    int rbB = (wn * 64 + l15) * 32 + cslot;

#define STAGE_P(buf, kb) do { \
    gl2lds16(gA0h + (kb), &smem[buf][0][ld0]); \
    gl2lds16(gA1h + (kb), &smem[buf][0][ld1]); \
    gl2lds16(gA0l + (kb), &smem[buf][1][ld0]); \
    gl2lds16(gA1l + (kb), &smem[buf][1][ld1]); \
    gl2lds16(gB0h + (kb), &smem[buf][2][ld0]); \
    gl2lds16(gB1h + (kb), &smem[buf][2][ld1]); \
    gl2lds16(gB0l + (kb), &smem[buf][3][ld0]); \
    gl2lds16(gB1l + (kb), &smem[buf][3][ld1]); \
} while (0)

    floatx4 acch[4][4], accx[4][4];
#pragma unroll
    for (int i = 0; i < 4; ++i)
#pragma unroll
        for (int j = 0; j < 4; ++j)
#pragma unroll
            for (int r = 0; r < 4; ++r) { acch[i][j][r] = 0.f; accx[i][j][r] = 0.f; }

    STAGE_P(0, 0);
    __syncthreads();
    int cur = 0;
    for (int it = 0; it < 16; ++it) {
        if (it < 15) STAGE_P(cur ^ 1, (it + 1) * 32);
        const _Float16* sAh = &smem[cur][0][0];
        const _Float16* sAl = &smem[cur][1][0];
        const _Float16* sBh = &smem[cur][2][0];
        const _Float16* sBl = &smem[cur][3][0];
        half8v afh[4], afl[4], bfh[4], bfl[4];
#pragma unroll
        for (int tm = 0; tm < 4; ++tm) {
            afh[tm] = *(const half8v*)&sAh[rbA + tm * 512];
            afl[tm] = *(const half8v*)&sAl[rbA + tm * 512];
        }
#pragma unroll
        for (int tn = 0; tn < 4; ++tn) {
            bfh[tn] = *(const half8v*)&sBh[rbB + tn * 512];
            bfl[tn] = *(const half8v*)&sBl[rbB + tn * 512];
        }
#pragma unroll
        for (int tm = 0; tm < 4; ++tm)
#pragma unroll
            for (int tn = 0; tn < 4; ++tn) {
                acch[tm][tn] = __builtin_amdgcn_mfma_f32_16x16x32_f16(afh[tm], bfh[tn], acch[tm][tn], 0, 0, 0);
                accx[tm][tn] = __builtin_amdgcn_mfma_f32_16x16x32_f16(afh[tm], bfl[tn], accx[tm][tn], 0, 0, 0);
                accx[tm][tn] = __builtin_amdgcn_mfma_f32_16x16x32_f16(afl[tm], bfh[tn], accx[tm][tn], 0, 0, 0);
            }
        __syncthreads();
        cur ^= 1;
    }
#undef STAGE_P
#pragma unroll
    for (int tm = 0; tm < 4; ++tm)
#pragma unroll
        for (int reg = 0; reg < 4; ++reg) {
            int m = m0 + wm * 64 + tm * 16 + quad * 4 + reg;
            if (m < M) {
#pragma unroll
                for (int tn = 0; tn < 4; ++tn) {
                    int n = n0 + wn * 64 + tn * 16 + l15;
                    u[(size_t)m * 1536 + n] = acch[tm][tn][reg] + accx[tm][tn][reg] * (1.0f / 4096.0f);
                }
            }
        }
}

// ---------------- pmat: P[c][tap*512+dout] = (W3_tap e_c), all 4096 codes ----------------
// k_phi skeleton, identity gather; DUAL-SPLIT output: Ph fp16 + Pl fp16 (x4096).
__global__ __launch_bounds__(256, 2) void k_pmat(const _Float16* __restrict__ eh,
        const _Float16* __restrict__ el, const _Float16* __restrict__ wh,
        const _Float16* __restrict__ wl, _Float16* __restrict__ Ph,
        _Float16* __restrict__ Pl0, _Float16* __restrict__ Pl1,
        _Float16* __restrict__ Pl2) {
    __shared__ _Float16 smem[2][4][4096] __attribute__((aligned(16)));  // 64KB
    int tid = threadIdx.x;
    int lane = tid & 63, wave = tid >> 6;
    int wm = wave >> 1, wn = wave & 1;
    int quad = lane >> 4, l15 = lane & 15;
    int m0 = blockIdx.x * 128, n0 = blockIdx.y * 128;

    int slot = lane & 3;
    int r0 = wave * 32 + (lane >> 2);
    int r1 = r0 + 16;
    int sc0 = (slot ^ ((r0 >> 1) & 3)) << 3;
    int sc1 = (slot ^ ((r1 >> 1) & 3)) << 3;
    int code0 = m0 + r0;   // identity gather
    int code1 = m0 + r1;
    const _Float16* gA0h = eh + (size_t)code0 * 512 + sc0;
    const _Float16* gA1h = eh + (size_t)code1 * 512 + sc1;
    const _Float16* gA0l = el + (size_t)code0 * 512 + sc0;
    const _Float16* gA1l = el + (size_t)code1 * 512 + sc1;
    const _Float16* gB0h = wh + (size_t)(n0 + r0) * 512 + sc0;
    const _Float16* gB1h = wh + (size_t)(n0 + r1) * 512 + sc1;
    const _Float16* gB0l = wl + (size_t)(n0 + r0) * 512 + sc0;
    const _Float16* gB1l = wl + (size_t)(n0 + r1) * 512 + sc1;
    int ld0 = wave * 1024;
    int ld1 = ld0 + 512;

    int cslot = (quad ^ ((l15 >> 1) & 3)) << 3;
    int rbA = (wm * 64 + l15) * 32 + cslot;
    int rbB = (wn * 64 + l15) * 32 + cslot;

#define STAGE_M(buf, kb) do { \
    gl2lds16(gA0h + (kb), &smem[buf][0][ld0]); \
    gl2lds16(gA1h + (kb), &smem[buf][0][ld1]); \
    gl2lds16(gA0l + (kb), &smem[buf][1][ld0]); \
    gl2lds16(gA1l + (kb), &smem[buf][1][ld1]); \
    gl2lds16(gB0h + (kb), &smem[buf][2][ld0]); \
    gl2lds16(gB1h + (kb), &smem[buf][2][ld1]); \
    gl2lds16(gB0l + (kb), &smem[buf][3][ld0]); \
    gl2lds16(gB1l + (kb), &smem[buf][3][ld1]); \
} while (0)

    floatx4 acch[4][4], accx[4][4];
#pragma unroll
    for (int i = 0; i < 4; ++i)
#pragma unroll
        for (int j = 0; j < 4; ++j)
#pragma unroll
            for (int r = 0; r < 4; ++r) { acch[i][j][r] = 0.f; accx[i][j][r] = 0.f; }

    STAGE_M(0, 0);
    __syncthreads();
    int cur = 0;
    for (int it = 0; it < 16; ++it) {
        if (it < 15) STAGE_M(cur ^ 1, (it + 1) * 32);
        const _Float16* sAh = &smem[cur][0][0];
        const _Float16* sAl = &smem[cur][1][0];
        const _Float16* sBh = &smem[cur][2][0];
        const _Float16* sBl = &smem[cur][3][0];
        half8v afh[4], afl[4], bfh[4], bfl[4];
#pragma unroll
        for (int tm = 0; tm < 4; ++tm) {
            afh[tm] = *(const half8v*)&sAh[rbA + tm * 512];
            afl[tm] = *(const half8v*)&sAl[rbA + tm * 512];
        }
#pragma unroll
        for (int tn = 0; tn < 4; ++tn) {
            bfh[tn] = *(const half8v*)&sBh[rbB + tn * 512];
            bfl[tn] = *(const half8v*)&sBl[rbB + tn * 512];
        }
#pragma unroll
        for (int tm = 0; tm < 4; ++tm)
#pragma unroll
            for (int tn = 0; tn < 4; ++tn) {
                acch[tm][tn] = __builtin_amdgcn_mfma_f32_16x16x32_f16(afh[tm], bfh[tn], acch[tm][tn], 0, 0, 0);
                accx[tm][tn] = __builtin_amdgcn_mfma_f32_16x16x32_f16(afh[tm], bfl[tn], accx[tm][tn], 0, 0, 0);
                accx[tm][tn] = __builtin_amdgcn_mfma_f32_16x16x32_f16(afl[tm], bfh[tn], accx[tm][tn], 0, 0, 0);
            }
        __syncthreads();
        cur ^= 1;
    }
#undef STAGE_M
#pragma unroll
    for (int tm = 0; tm < 4; ++tm)
#pragma unroll
        for (int reg = 0; reg < 4; ++reg) {
            int m = m0 + wm * 64 + tm * 16 + quad * 4 + reg;
            _Float16* plr = plrow(Pl0, Pl1, Pl2, m);
#pragma unroll
            for (int tn = 0; tn < 4; ++tn) {
                int n = n0 + wn * 64 + tn * 16 + l15;
                float val = acch[tm][tn][reg] + accx[tm][tn][reg] * (1.0f / 4096.0f);
                HL r = split2(val);
                Ph[(size_t)m * 1536 + n] = r.h;
                plr[n] = r.l;
            }
        }
}

// combine (s<=64, u-path): resid = rsrc - (0.5*h + 0.5*(conv+bias))
__global__ __launch_bounds__(256) void k_combine(const float* __restrict__ u,
        const float* __restrict__ embed, const unsigned long long* __restrict__ minbuf,
        const float* __restrict__ bias, const float* __restrict__ rsrc,
        float* __restrict__ resid, int s, float scale) {
    int tid = threadIdx.x;
    int m = blockIdx.x * 2 + (tid >> 7);
    int d4 = (tid & 127) << 2;
    int b = m >> 9, t = m & 511;
    int bs = b * s;
    float4 bi = *(const float4*)(bias + d4);
    float uu = ((float)t + 0.5f) * scale - 0.5f;
    float fl = floorf(uu);
    float w = uu - fl;
    int i0 = (int)fl, i1 = i0 + 1;
    i0 = min(max(i0, 0), s - 1);
    i1 = min(max(i1, 0), s - 1);
    int c0 = (int)(unsigned)minbuf[bs + i0];
    int c1 = (int)(unsigned)minbuf[bs + i1];
    float4 e0 = *(const float4*)(embed + (size_t)c0 * 512 + d4);
    float4 e1 = *(const float4*)(embed + (size_t)c1 * 512 + d4);
    float om = 1.0f - w;
    float4 h4;
    h4.x = om * e0.x + w * e1.x; h4.y = om * e0.y + w * e1.y;
    h4.z = om * e0.z + w * e1.z; h4.w = om * e0.w + w * e1.w;
    float4 conv = make_float4(0.f, 0.f, 0.f, 0.f);
#pragma unroll
    for (int tap = 0; tap < 3; ++tap) {
        int tt = t + tap - 1;
        if (tt >= 0 && tt < 512) {
            float uu2 = ((float)tt + 0.5f) * scale - 0.5f;
            float fl2 = floorf(uu2);
            float w2 = uu2 - fl2;
            int j0 = (int)fl2, j1 = j0 + 1;
            j0 = min(max(j0, 0), s - 1);
            j1 = min(max(j1, 0), s - 1);
            float4 a4 = *(const float4*)(u + (size_t)(bs + j0) * 1536 + tap * 512 + d4);
            float4 b4 = *(const float4*)(u + (size_t)(bs + j1) * 1536 + tap * 512 + d4);
            float ow = 1.0f - w2;
            conv.x += ow * a4.x + w2 * b4.x;
            conv.y += ow * a4.y + w2 * b4.y;
            conv.z += ow * a4.z + w2 * b4.z;
            conv.w += ow * a4.w + w2 * b4.w;
        }
    }
    size_t off = (size_t)m * 512 + d4;
    float4 rv = *(const float4*)(rsrc + off);
    rv.x -= 0.5f * h4.x + 0.5f * (conv.x + bi.x);
    rv.y -= 0.5f * h4.y + 0.5f * (conv.y + bi.y);
    rv.z -= 0.5f * h4.z + 0.5f * (conv.z + bi.z);
    rv.w -= 0.5f * h4.w + 0.5f * (conv.w + bi.w);
    *(float4*)(resid + off) = rv;
}

// combineP (s in {128,256,512}): conv via code-indexed dual-split P lerps.
// resid = rsrc - (0.5*h + 0.5*(conv+bias)); s==512 -> w2==0, single gather.
__global__ __launch_bounds__(256) void k_combineP(const _Float16* __restrict__ Ph,
        const _Float16* __restrict__ Pl0, const _Float16* __restrict__ Pl1,
        const _Float16* __restrict__ Pl2,
        const float* __restrict__ embed, const unsigned long long* __restrict__ minbuf,
        const float* __restrict__ bias, const float* __restrict__ rsrc,
        float* __restrict__ resid, int s, float scale) {
    int tid = threadIdx.x;
    int m = blockIdx.x * 2 + (tid >> 7);
    int d4 = (tid & 127) << 2;
    int b = m >> 9, t = m & 511;
    int bs = b * s;
    int noint = (s == 512);
    float4 bi = *(const float4*)(bias + d4);
    float uu = ((float)t + 0.5f) * scale - 0.5f;
    float fl = floorf(uu);
    float w = uu - fl;
    int i0 = (int)fl, i1 = i0 + 1;
    i0 = min(max(i0, 0), s - 1);
    i1 = min(max(i1, 0), s - 1);
    int c0 = (int)(unsigned)minbuf[bs + i0];
    int c1 = (int)(unsigned)minbuf[bs + i1];
    float4 e0 = *(const float4*)(embed + (size_t)c0 * 512 + d4);
    float4 e1 = *(const float4*)(embed + (size_t)c1 * 512 + d4);
    float om = 1.0f - w;
    float4 h4;
    h4.x = om * e0.x + w * e1.x; h4.y = om * e0.y + w * e1.y;
    h4.z = om * e0.z + w * e1.z; h4.w = om * e0.w + w * e1.w;
    float4 conv = make_float4(0.f, 0.f, 0.f, 0.f);
#pragma unroll
    for (int tap = 0; tap < 3; ++tap) {
        int tt = t + tap - 1;
        if (tt >= 0 && tt < 512) {
            float uu2 = ((float)tt + 0.5f) * scale - 0.5f;
            float fl2 = floorf(uu2);
            float w2 = uu2 - fl2;
            int j0 = (int)fl2, j1 = j0 + 1;
            j0 = min(max(j0, 0), s - 1);
            j1 = min(max(j1, 0), s - 1);
            int cc0 = (int)(unsigned)minbuf[bs + j0];
            size_t oseg = tap * 512 + d4;
            half4v ah = *(const half4v*)(Ph + (size_t)cc0 * 1536 + oseg);
            half4v al = *(const half4v*)(plrowc(Pl0, Pl1, Pl2, cc0) + oseg);
            if (noint) {
                // w2 == 0 exactly: conv += av
#pragma unroll
                for (int q = 0; q < 4; ++q) {
                    float av = (float)ah[q] + (float)al[q] * (1.0f / 4096.0f);
                    float* cp = q == 0 ? &conv.x : q == 1 ? &conv.y : q == 2 ? &conv.z : &conv.w;
                    *cp += av;
                }
            } else {
                int cc1 = (int)(unsigned)minbuf[bs + j1];
                half4v bh = *(const half4v*)(Ph + (size_t)cc1 * 1536 + oseg);
                half4v bl = *(const half4v*)(plrowc(Pl0, Pl1, Pl2, cc1) + oseg);
                float ow = 1.0f - w2;
#pragma unroll
                for (int q = 0; q < 4; ++q) {
                    float av = (float)ah[q] + (float)al[q] * (1.0f / 4096.0f);
                    float bv = (float)bh[q] + (float)bl[q] * (1.0f / 4096.0f);
                    float* cp = q == 0 ? &conv.x : q == 1 ? &conv.y : q == 2 ? &conv.z : &conv.w;
                    *cp += ow * av + w2 * bv;
                }
            }
        }
    }
    size_t off = (size_t)m * 512 + d4;
    float4 rv = *(const float4*)(rsrc + off);
    rv.x -= 0.5f * h4.x + 0.5f * (conv.x + bi.x);
    rv.y -= 0.5f * h4.y + 0.5f * (conv.y + bi.y);
    rv.z -= 0.5f * h4.z + 0.5f * (conv.z + bi.z);
    rv.w -= 0.5f * h4.w + 0.5f * (conv.w + bi.w);
    *(float4*)(resid + off) = rv;
}

__global__ __launch_bounds__(256) void k_final(const float* __restrict__ x,
        const float* __restrict__ resid, float* __restrict__ out) {
    int gid = blockIdx.x * 256 + threadIdx.x;
    float4 xv = ((const float4*)x)[gid];
    float4 rv = ((const float4*)resid)[gid];
    float4 o;
    o.x = xv.x - rv.x; o.y = xv.y - rv.y; o.z = xv.z - rv.z; o.w = xv.w - rv.w;
    ((float4*)out)[gid] = o;
}

extern "C" void kernel_launch(void* const* d_in, const int* in_sizes, int n_in,
                              void* d_out, int out_size, void* d_ws, size_t ws_size,
                              hipStream_t stream) {
    const float* x     = (const float*)d_in[0];
    const float* embed = (const float*)d_in[1];
    const float* pw    = (const float*)d_in[2];
    const float* pb    = (const float*)d_in[3];
    float* out = (float*)d_out;

    // ws layout (floats), ~59.1 MB:
    // resid 16MB | U 16MB (zh/zl; u aliases, s<=64) | ehi/elo 8MB |
    // Wt2 hi/lo 12MB (kp0-2 rows reused as Pl segs after si=6) |
    // esq 16KB | minbuf 64KB | bm2 4MB | Pl tail 3MB
    // Ph (fp16, 12.6MB) lives in d_out (out written only by k_final).
    float* resid = (float*)d_ws;
    float* Ubase = resid + 4194304;
    _Float16* zh = (_Float16*)Ubase;
    _Float16* zl = zh + 4194304;
    float* u = Ubase;
    _Float16* ehi = (_Float16*)(Ubase + 4194304);
    _Float16* elo = ehi + 2097152;
    _Float16* whi = elo + 2097152;
    _Float16* wlo = whi + 3145728;
    float* esq = (float*)(wlo + 3145728);
    unsigned long long* minbuf = (unsigned long long*)(esq + 4096);
    unsigned long long* bm2 = (unsigned long long*)(minbuf + 8192);
    _Float16* Ph = (_Float16*)d_out;
    _Float16* Pl0 = whi;                        // rows 0..1535   (dead kp0-2)
    _Float16* Pl1 = wlo;                        // rows 1536..3071 (dead kp0-2)
    _Float16* Pl2 = (_Float16*)(bm2 + 524288);  // rows 3072..4095 (3MB tail)

    k_prep_embed<<<1024, 256, 0, stream>>>(embed, ehi, elo, esq);
    k_split_w<<<12288, 256, 0, stream>>>(pw, whi, wlo);

    const int SCv[10] = {1, 2, 4, 8, 16, 32, 64, 128, 256, 512};
    // PHI_IDX with float64-ulp tie-breaks at si=2 and si=7 (verified round 2)
    const int PIv[10] = {0, 0, 1, 1, 1, 2, 2, 3, 3, 3};
    for (int si = 0; si < 10; ++si) {
        int s = SCv[si];
        int M = 16 * s;
        int kp = PIv[si];
        int lg = __builtin_ctz((unsigned)s);
        float scale = (float)s / 512.0f;
        const float* src = (si == 0) ? x : resid;
        if (s <= 8)
            k_zmean_s<<<16 * s * 8, 256, 0, stream>>>(src, zh, zl, s, lg);
        else
            k_zmean<<<(M * 512) / 256, 256, 0, stream>>>(src, zh, zl, s, lg);
        k_dist1<<<dim3((M + 127) / 128, 32), 256, 0, stream>>>(zh, ehi, esq, bm2, M);
        k_refine<<<(M + 3) / 4, 256, 0, stream>>>(zh, zl, embed, bm2, minbuf, M);
        if (si <= 6) {
            k_phi<<<dim3((M + 127) / 128, 12), 256, 0, stream>>>(ehi, elo,
                    whi + (size_t)kp * 1536 * 512, wlo + (size_t)kp * 1536 * 512, minbuf, u, M);
            k_combine<<<4096, 256, 0, stream>>>(u, embed, minbuf, pb + kp * 512, src, resid, s, scale);
        } else {
            if (si == 7)
                k_pmat<<<dim3(32, 12), 256, 0, stream>>>(ehi, elo,
                        whi + (size_t)3 * 1536 * 512, wlo + (size_t)3 * 1536 * 512,
                        Ph, Pl0, Pl1, Pl2);
            k_combineP<<<4096, 256, 0, stream>>>(Ph, Pl0, Pl1, Pl2, embed, minbuf,
                    pb + 3 * 512, src, resid, s, scale);
        }
    }
    k_final<<<4096, 256, 0, stream>>>(x, resid, out);
}